// Round 1
// baseline (607.728 us; speedup 1.0000x reference)
//
#include <hip/hip_runtime.h>

#define GO_H 19
#define GO_HP 21            // padded dim (halo of 1)
#define NCELL (GO_H * GO_H) // 361
#define NPAD  (GO_HP * GO_HP) // 441

__global__ __launch_bounds__(256) void go_features_kernel(
    const float* __restrict__ stones,      // (B, 2, 19, 19)
    const int*   __restrict__ cur_player,  // (B,)
    const int*   __restrict__ ko,          // (B, 2)
    float*       __restrict__ out)         // (B, 5, 19, 19)
{
    __shared__ float cur_p[NPAD];
    __shared__ float opp_p[NPAD];
    __shared__ float emp_p[NPAD];
    __shared__ float weak_p[NPAD];

    const int b   = blockIdx.x;
    const int tid = threadIdx.x;
    const int cp  = cur_player[b];

    const long long ibase = (long long)b * (2 * NCELL);
    const long long obase = (long long)b * (5 * NCELL);

    // Zero the padded planes (halo must be 0 to match jnp.pad semantics).
    for (int i = tid; i < NPAD; i += 256) {
        cur_p[i]  = 0.f;
        opp_p[i]  = 0.f;
        emp_p[i]  = 0.f;
        weak_p[i] = 0.f;
    }
    __syncthreads();

    // Phase 1: load stones, classify into cur/opp/empty, fill interior.
    #pragma unroll
    for (int k = 0; k < 2; ++k) {
        int c = tid + k * 256;
        if (c < NCELL) {
            float s0 = stones[ibase + c];
            float s1 = stones[ibase + NCELL + c];
            float cu = cp ? s1 : s0;
            float op = cp ? s0 : s1;
            float em = 1.0f - s0 - s1;
            int r = c / GO_H, col = c % GO_H;
            int pi = (r + 1) * GO_HP + (col + 1);
            cur_p[pi] = cu;
            opp_p[pi] = op;
            emp_p[pi] = em;
        }
    }
    __syncthreads();

    // Phase 2: weak = (opp > 0.5) & (nbr(opp) == 1)
    #pragma unroll
    for (int k = 0; k < 2; ++k) {
        int c = tid + k * 256;
        if (c < NCELL) {
            int r = c / GO_H, col = c % GO_H;
            int pi = (r + 1) * GO_HP + (col + 1);
            float opl = opp_p[pi - GO_HP] + opp_p[pi + GO_HP]
                      + opp_p[pi - 1]     + opp_p[pi + 1];
            weak_p[pi] = (opp_p[pi] > 0.5f && opl == 1.0f) ? 1.f : 0.f;
        }
    }
    __syncthreads();

    // Per-board scalars.
    int kr = ko[2 * b], kc = ko[2 * b + 1];
    bool has_ko = (kr >= 0);
    int rr = min(max(kr, 0), GO_H - 1);
    int cc = min(max(kc, 0), GO_H - 1);
    int koc = rr * GO_H + cc;
    float turn = (float)cp;

    // Phase 3: legal, cur_lib, stores.
    #pragma unroll
    for (int k = 0; k < 2; ++k) {
        int c = tid + k * 256;
        if (c < NCELL) {
            int r = c / GO_H, col = c % GO_H;
            int pi = (r + 1) * GO_HP + (col + 1);
            float em  = emp_p[pi];
            bool  emb = em > 0.5f;
            float ne = emp_p[pi - GO_HP] + emp_p[pi + GO_HP]
                     + emp_p[pi - 1]     + emp_p[pi + 1];
            float nw = weak_p[pi - GO_HP] + weak_p[pi + GO_HP]
                     + weak_p[pi - 1]     + weak_p[pi + 1];
            bool legal = emb && (ne > 0.f || nw > 0.f);
            if (has_ko && c == koc) legal = false;
            float nc = cur_p[pi - GO_HP] + cur_p[pi + GO_HP]
                     + cur_p[pi - 1]     + cur_p[pi + 1];

            out[obase + c]             = cur_p[pi];
            out[obase + NCELL + c]     = opp_p[pi];
            out[obase + 2 * NCELL + c] = legal ? 1.f : 0.f;
            out[obase + 3 * NCELL + c] = nc * em;
            out[obase + 4 * NCELL + c] = turn;
        }
    }
}

extern "C" void kernel_launch(void* const* d_in, const int* in_sizes, int n_in,
                              void* d_out, int out_size, void* d_ws, size_t ws_size,
                              hipStream_t stream) {
    const float* stones     = (const float*)d_in[0];
    const int*   cur_player = (const int*)d_in[1];
    const int*   ko         = (const int*)d_in[2];
    float*       out        = (float*)d_out;

    const int B = in_sizes[1];  // current_player has B elements
    go_features_kernel<<<B, 256, 0, stream>>>(stones, cur_player, ko, out);
}

// Round 2
// 583.343 us; speedup vs baseline: 1.0418x; 1.0418x over previous
//
#include <hip/hip_runtime.h>

#define GO_H 19
#define NCELL 361            // 19*19
#define G 4                  // boards per block
#define NIN (G * 2 * NCELL)  // input floats per group = 2888
#define NC_G (G * NCELL)     // cells per group = 1444

__global__ __launch_bounds__(256) void go_features_kernel(
    const float* __restrict__ stones,      // (B, 2, 19, 19)
    const int*   __restrict__ cur_player,  // (B,)
    const int*   __restrict__ ko,          // (B, 2)
    float*       __restrict__ out,         // (B, 5, 19, 19)
    int B)
{
    __shared__ float sarr[NIN];      // raw stones for G boards, flat global layout
    __shared__ float weak_s[NC_G];   // weak plane per board
    __shared__ int   cp_s[G];
    __shared__ int   koc_s[G];       // ko cell index or -1
    __shared__ int   opp_off_s[G];   // base offset of opp plane in sarr

    const int tid = threadIdx.x;
    const int gb  = blockIdx.x * G;

    // Stage group inputs as float4 (group base is 16B-aligned: gb*722*4 bytes).
    {
        const float4* in4 = (const float4*)(stones + (size_t)gb * (2 * NCELL));
        float4* s4 = (float4*)sarr;
        #pragma unroll
        for (int i = tid; i < NIN / 4; i += 256) s4[i] = in4[i];
    }

    if (tid < G) {
        int b  = gb + tid;
        int cp = cur_player[b];
        cp_s[tid] = cp;
        opp_off_s[tid] = tid * (2 * NCELL) + (cp == 0 ? NCELL : 0);
        int kr = ko[2 * b], kc = ko[2 * b + 1];
        int rr = min(max(kr, 0), GO_H - 1);
        int cc = min(max(kc, 0), GO_H - 1);
        koc_s[tid] = (kr >= 0) ? (rr * GO_H + cc) : -1;
    }
    __syncthreads();

    // Phase 2: weak = (opp > 0.5) && (nbr(opp) == 1)
    for (int i = tid; i < NC_G; i += 256) {
        int g   = i / NCELL;
        int c   = i - g * NCELL;
        int r   = c / GO_H;
        int col = c - r * GO_H;
        int ob  = opp_off_s[g];

        float mu = (r > 0)          ? 1.f : 0.f;
        float md = (r < GO_H - 1)   ? 1.f : 0.f;
        float ml = (col > 0)        ? 1.f : 0.f;
        float mr = (col < GO_H - 1) ? 1.f : 0.f;
        int iu = (r > 0)          ? c - GO_H : c;
        int id = (r < GO_H - 1)   ? c + GO_H : c;
        int il = (col > 0)        ? c - 1    : c;
        int ir = (col < GO_H - 1) ? c + 1    : c;

        float opl = sarr[ob + iu] * mu + sarr[ob + id] * md
                  + sarr[ob + il] * ml + sarr[ob + ir] * mr;
        float osf = sarr[ob + c];
        weak_s[i] = (osf > 0.5f && opl == 1.0f) ? 1.f : 0.f;
    }
    __syncthreads();

    // Phase 3: legal, cur_lib, and all 5 output planes.
    for (int i = tid; i < NC_G; i += 256) {
        int g   = i / NCELL;
        int c   = i - g * NCELL;
        int r   = c / GO_H;
        int col = c - r * GO_H;
        int base = g * (2 * NCELL);
        int cp   = cp_s[g];
        int wb   = g * NCELL;

        float mu = (r > 0)          ? 1.f : 0.f;
        float md = (r < GO_H - 1)   ? 1.f : 0.f;
        float ml = (col > 0)        ? 1.f : 0.f;
        float mr = (col < GO_H - 1) ? 1.f : 0.f;
        int iu = (r > 0)          ? c - GO_H : c;
        int id = (r < GO_H - 1)   ? c + GO_H : c;
        int il = (col > 0)        ? c - 1    : c;
        int ir = (col < GO_H - 1) ? c + 1    : c;

        float s0 = sarr[base + c];
        float s1 = sarr[base + NCELL + c];
        float cu = cp ? s1 : s0;
        float op = cp ? s0 : s1;
        float em = 1.f - s0 - s1;

        float ne = 0.f, ncur = 0.f;
        {
            float n0, n1;
            n0 = sarr[base + iu]; n1 = sarr[base + NCELL + iu];
            ne += (1.f - n0 - n1) * mu;  ncur += (cp ? n1 : n0) * mu;
            n0 = sarr[base + id]; n1 = sarr[base + NCELL + id];
            ne += (1.f - n0 - n1) * md;  ncur += (cp ? n1 : n0) * md;
            n0 = sarr[base + il]; n1 = sarr[base + NCELL + il];
            ne += (1.f - n0 - n1) * ml;  ncur += (cp ? n1 : n0) * ml;
            n0 = sarr[base + ir]; n1 = sarr[base + NCELL + ir];
            ne += (1.f - n0 - n1) * mr;  ncur += (cp ? n1 : n0) * mr;
        }
        float nw = weak_s[wb + iu] * mu + weak_s[wb + id] * md
                 + weak_s[wb + il] * ml + weak_s[wb + ir] * mr;

        bool emb   = em > 0.5f;
        bool legal = emb && (ne > 0.f || nw > 0.f);
        if (c == koc_s[g]) legal = false;

        size_t obase = (size_t)(gb + g) * (5 * NCELL);
        out[obase + c]             = cu;
        out[obase + NCELL + c]     = op;
        out[obase + 2 * NCELL + c] = legal ? 1.f : 0.f;
        out[obase + 3 * NCELL + c] = ncur * em;
        out[obase + 4 * NCELL + c] = (float)cp;
    }
}

extern "C" void kernel_launch(void* const* d_in, const int* in_sizes, int n_in,
                              void* d_out, int out_size, void* d_ws, size_t ws_size,
                              hipStream_t stream) {
    const float* stones     = (const float*)d_in[0];
    const int*   cur_player = (const int*)d_in[1];
    const int*   ko         = (const int*)d_in[2];
    float*       out        = (float*)d_out;

    const int B = in_sizes[1];          // current_player has B elements
    const int nblocks = B / G;          // B = 65536 divisible by 4
    go_features_kernel<<<nblocks, 256, 0, stream>>>(stones, cur_player, ko, out, B);
}